// Round 1
// baseline (1073.236 us; speedup 1.0000x reference)
//
#include <hip/hip_runtime.h>
#include <math.h>

// ---------------------------------------------------------------------------
// GraphNet: 3x EdgeConv (restructured) + GAT(2 heads, concat=False)
//
// EdgeConv restructure:
//   msg_e = hn[src] @ wc_top + ef_e @ wc_bot + bc
//         = h[src] @ (wn@wc_top) + ea_e @ (we@wc_bot) + (bn@wc_top + be@wc_bot + bc)
//         = p[src] + q_e
//   out[d] = sum_{e: dst(e)=d} (p[src_e] + q_e)      (CSR gather, no atomics)
// ---------------------------------------------------------------------------

#define TPB 256

// ---------------- CSR build ----------------
__global__ __launch_bounds__(TPB) void k_hist(const int* __restrict__ dst, int* __restrict__ deg, int E) {
    int e = blockIdx.x * TPB + threadIdx.x;
    if (e < E) atomicAdd(&deg[dst[e]], 1);
}

__global__ __launch_bounds__(TPB) void k_scan1(int* __restrict__ data, int* __restrict__ partials, int n) {
    __shared__ int s[TPB];
    int i = blockIdx.x * TPB + threadIdx.x;
    int v = (i < n) ? data[i] : 0;
    s[threadIdx.x] = v;
    __syncthreads();
    for (int off = 1; off < TPB; off <<= 1) {
        int t = (threadIdx.x >= off) ? s[threadIdx.x - off] : 0;
        __syncthreads();
        s[threadIdx.x] += t;
        __syncthreads();
    }
    if (i < n) data[i] = s[threadIdx.x] - v;  // exclusive
    if (threadIdx.x == TPB - 1) partials[blockIdx.x] = s[TPB - 1];
}

__global__ __launch_bounds__(1024) void k_scan2(int* __restrict__ partials, int nb) {
    __shared__ int s[1024];
    int v = (threadIdx.x < nb) ? partials[threadIdx.x] : 0;
    s[threadIdx.x] = v;
    __syncthreads();
    for (int off = 1; off < 1024; off <<= 1) {
        int t = (threadIdx.x >= off) ? s[threadIdx.x - off] : 0;
        __syncthreads();
        s[threadIdx.x] += t;
        __syncthreads();
    }
    if (threadIdx.x < nb) partials[threadIdx.x] = s[threadIdx.x] - v;  // exclusive
}

__global__ __launch_bounds__(TPB) void k_scan3(int* __restrict__ data, const int* __restrict__ partials,
                                               int* __restrict__ cursor, int n, int total) {
    int i = blockIdx.x * TPB + threadIdx.x;
    if (i < n) {
        int v = data[i] + partials[blockIdx.x];
        data[i] = v;
        cursor[i] = v;
    }
    if (i == 0) data[n] = total;
}

__global__ __launch_bounds__(TPB) void k_scatter(const int* __restrict__ src, const int* __restrict__ dst,
                                                 int* __restrict__ cursor, int* __restrict__ csr_e,
                                                 int* __restrict__ csr_src, int E) {
    int e = blockIdx.x * TPB + threadIdx.x;
    if (e < E) {
        int d = dst[e];
        int idx = atomicAdd(&cursor[d], 1);
        csr_e[idx] = e;
        csr_src[idx] = src[e];
    }
}

// ---------------- weight folding (per layer, 1 block) ----------------
// W1 = wn @ wc_top [64x64]; W2 = we @ wc_bot [5x64]; c = bn@wc_top + be@wc_bot + bc [64]
__global__ __launch_bounds__(TPB) void k_combine(const float* __restrict__ wn, const float* __restrict__ bn,
                                                 const float* __restrict__ we, const float* __restrict__ be,
                                                 const float* __restrict__ wc, const float* __restrict__ bc,
                                                 float* __restrict__ W1, float* __restrict__ W2,
                                                 float* __restrict__ cv) {
    int tid = threadIdx.x;
    for (int idx = tid; idx < 64 * 64; idx += TPB) {
        int i = idx >> 6, j = idx & 63;
        float acc = 0.f;
        #pragma unroll 8
        for (int k = 0; k < 64; k++) acc = fmaf(wn[i * 64 + k], wc[k * 64 + j], acc);
        W1[idx] = acc;
    }
    for (int idx = tid; idx < 5 * 64; idx += TPB) {
        int i = idx >> 6, j = idx & 63;
        float acc = 0.f;
        #pragma unroll 8
        for (int k = 0; k < 64; k++) acc = fmaf(we[i * 64 + k], wc[(64 + k) * 64 + j], acc);
        W2[idx] = acc;
    }
    for (int j = tid; j < 64; j += TPB) {
        float acc = bc[j];
        for (int k = 0; k < 64; k++) {
            acc = fmaf(bn[k], wc[k * 64 + j], acc);
            acc = fmaf(be[k], wc[(64 + k) * 64 + j], acc);
        }
        cv[j] = acc;
    }
}

// ---------------- dense GEMM: P[N,64] = act(H[N,64]) @ W[64,64] ----------------
__global__ __launch_bounds__(TPB) void k_gemm64(const float* __restrict__ H, const float* __restrict__ W,
                                                float* __restrict__ P, int n, int relu_in) {
    __shared__ float Ws[64 * 64];
    for (int i = threadIdx.x; i < 64 * 64; i += TPB) Ws[i] = W[i];
    __syncthreads();
    int wave = threadIdx.x >> 6, lane = threadIdx.x & 63;
    for (int row = blockIdx.x * 4 + wave; row < n; row += gridDim.x * 4) {
        float hv = H[row * 64 + lane];
        if (relu_in) hv = fmaxf(hv, 0.f);
        float acc = 0.f;
        #pragma unroll
        for (int k = 0; k < 64; k++) acc = fmaf(__shfl(hv, k), Ws[k * 64 + lane], acc);
        P[row * 64 + lane] = acc;
    }
}

// ---------------- GAT GEMM: G[N,128] = relu(H[N,64]) @ W[64,128] ----------------
__global__ __launch_bounds__(TPB) void k_gemm_gat(const float* __restrict__ H, const float* __restrict__ W,
                                                  float* __restrict__ G, int n) {
    __shared__ float Ws[64 * 128];
    for (int i = threadIdx.x; i < 64 * 128; i += TPB) Ws[i] = W[i];
    __syncthreads();
    int wave = threadIdx.x >> 6, lane = threadIdx.x & 63;
    for (int row = blockIdx.x * 4 + wave; row < n; row += gridDim.x * 4) {
        float hv = fmaxf(H[row * 64 + lane], 0.f);
        float a0 = 0.f, a1 = 0.f;
        #pragma unroll
        for (int k = 0; k < 64; k++) {
            float b = __shfl(hv, k);
            a0 = fmaf(b, Ws[k * 128 + lane], a0);
            a1 = fmaf(b, Ws[k * 128 + 64 + lane], a1);
        }
        G[row * 128 + lane] = a0;
        G[row * 128 + 64 + lane] = a1;
    }
}

// ---------------- EdgeConv aggregation: out[d] = sum_e p[src_e] + q_e ----------------
__global__ __launch_bounds__(TPB) void k_agg(const float* __restrict__ P, const int* __restrict__ row_start,
                                             const int* __restrict__ csr_e, const int* __restrict__ csr_src,
                                             const float* __restrict__ EA, const float* __restrict__ W2,
                                             const float* __restrict__ cv, float* __restrict__ OUT, int n) {
    int wave = threadIdx.x >> 6, lane = threadIdx.x & 63;
    float w2r0 = W2[0 * 64 + lane], w2r1 = W2[1 * 64 + lane], w2r2 = W2[2 * 64 + lane];
    float w2r3 = W2[3 * 64 + lane], w2r4 = W2[4 * 64 + lane];
    float cl = cv[lane];
    for (int node = blockIdx.x * 4 + wave; node < n; node += gridDim.x * 4) {
        int beg = row_start[node], end = row_start[node + 1];
        float acc = 0.f;
        for (int j = beg; j < end; j++) {
            int e = csr_e[j];
            int s = csr_src[j];
            float pv = P[s * 64 + lane];
            const float* eap = EA + (size_t)e * 5;
            float q = cl;
            q = fmaf(eap[0], w2r0, q);
            q = fmaf(eap[1], w2r1, q);
            q = fmaf(eap[2], w2r2, q);
            q = fmaf(eap[3], w2r3, q);
            q = fmaf(eap[4], w2r4, q);
            acc += pv + q;
        }
        OUT[node * 64 + lane] = acc;
    }
}

// ---------------- GAT attention scores ----------------
__global__ __launch_bounds__(128) void k_att(const float* __restrict__ G, const float* __restrict__ att_src,
                                             const float* __restrict__ att_dst, float* __restrict__ asrc,
                                             float* __restrict__ adst, int n) {
    int node = blockIdx.x;
    if (node >= n) return;
    int tid = threadIdx.x;              // 0..127  (= head*64 + c)
    float v = G[(size_t)node * 128 + tid];
    float s1 = v * att_src[tid];
    float s2 = v * att_dst[tid];
    #pragma unroll
    for (int off = 32; off > 0; off >>= 1) {
        s1 += __shfl_down(s1, off);
        s2 += __shfl_down(s2, off);
    }
    int lane = tid & 63;
    int head = tid >> 6;
    if (lane == 0) {
        asrc[node * 2 + head] = s1;
        adst[node * 2 + head] = s2;
    }
}

// ---------------- GAT aggregation (segment softmax + weighted sum) ----------------
__global__ __launch_bounds__(TPB) void k_gat_agg(const float* __restrict__ G, const int* __restrict__ row_start,
                                                 const int* __restrict__ csr_src, const float* __restrict__ asrc,
                                                 const float* __restrict__ adst, const float* __restrict__ bgat,
                                                 float* __restrict__ OUT, int n) {
    int wave = threadIdx.x >> 6, lane = threadIdx.x & 63;
    float bg = bgat[lane];
    for (int node = blockIdx.x * 4 + wave; node < n; node += gridDim.x * 4) {
        int beg = row_start[node], end = row_start[node + 1];
        float ad0 = adst[node * 2 + 0], ad1 = adst[node * 2 + 1];
        float m0 = -INFINITY, m1 = -INFINITY;
        for (int j = beg; j < end; j++) {
            int s = csr_src[j];
            float al0 = asrc[s * 2 + 0] + ad0;
            float al1 = asrc[s * 2 + 1] + ad1;
            al0 = (al0 > 0.f) ? al0 : 0.2f * al0;
            al1 = (al1 > 0.f) ? al1 : 0.2f * al1;
            m0 = fmaxf(m0, al0);
            m1 = fmaxf(m1, al1);
        }
        float d0 = 0.f, d1 = 0.f, A0 = 0.f, A1 = 0.f;
        for (int j = beg; j < end; j++) {
            int s = csr_src[j];
            float al0 = asrc[s * 2 + 0] + ad0;
            float al1 = asrc[s * 2 + 1] + ad1;
            al0 = (al0 > 0.f) ? al0 : 0.2f * al0;
            al1 = (al1 > 0.f) ? al1 : 0.2f * al1;
            float w0 = __expf(al0 - m0);
            float w1 = __expf(al1 - m1);
            d0 += w0;
            d1 += w1;
            A0 = fmaf(w0, G[(size_t)s * 128 + lane], A0);
            A1 = fmaf(w1, G[(size_t)s * 128 + 64 + lane], A1);
        }
        float r = 0.5f * (A0 / (d0 + 1e-16f) + A1 / (d1 + 1e-16f)) + bg;
        OUT[node * 64 + lane] = r;
    }
}

extern "C" void kernel_launch(void* const* d_in, const int* in_sizes, int n_in,
                              void* d_out, int out_size, void* d_ws, size_t ws_size,
                              hipStream_t stream) {
    const float* x   = (const float*)d_in[0];
    const int*   ei  = (const int*)d_in[1];
    const float* ea  = (const float*)d_in[2];
    const int N = in_sizes[0] / 64;
    const int E = in_sizes[1] / 2;
    const int* src = ei;
    const int* dst = ei + E;

    const float* wn[3] = {(const float*)d_in[3],  (const float*)d_in[9],  (const float*)d_in[15]};
    const float* bn[3] = {(const float*)d_in[4],  (const float*)d_in[10], (const float*)d_in[16]};
    const float* we[3] = {(const float*)d_in[5],  (const float*)d_in[11], (const float*)d_in[17]};
    const float* be[3] = {(const float*)d_in[6],  (const float*)d_in[12], (const float*)d_in[18]};
    const float* wc[3] = {(const float*)d_in[7],  (const float*)d_in[13], (const float*)d_in[19]};
    const float* bc[3] = {(const float*)d_in[8],  (const float*)d_in[14], (const float*)d_in[20]};
    const float* wgat    = (const float*)d_in[21];
    const float* att_src = (const float*)d_in[22];
    const float* att_dst = (const float*)d_in[23];
    const float* bgat    = (const float*)d_in[24];

    // workspace carve-up (all 256B aligned)
    char* ws = (char*)d_ws;
    size_t off = 0;
    auto alloc = [&](size_t bytes) -> void* {
        void* p = ws + off;
        off = (off + bytes + 255) & ~(size_t)255;
        return p;
    };
    int*   row_start = (int*)alloc((size_t)(N + 1) * 4);
    int*   cursor    = (int*)alloc((size_t)N * 4);
    int*   partials  = (int*)alloc(1024 * 4);
    int*   csr_e     = (int*)alloc((size_t)E * 4);
    int*   csr_src   = (int*)alloc((size_t)E * 4);
    float* Wc        = (float*)alloc((size_t)3 * 4480 * 4);   // per layer: W1(4096) W2(320) c(64)
    float* bufB      = (float*)alloc((size_t)N * 64 * 4);     // aggregation output (h)
    float* bufG      = (float*)alloc((size_t)N * 128 * 4);    // p (first half lifetime) then g
    float* asrc      = (float*)alloc((size_t)N * 2 * 4);
    float* adst      = (float*)alloc((size_t)N * 2 * 4);
    float* p = bufG;                                           // [N,64] while edge-conv layers run
    float* out = (float*)d_out;

    const int nbN = (N + TPB - 1) / TPB;
    const int nbE = (E + TPB - 1) / TPB;
    const int nodeBlocks = (N + 3) / 4;  // 1 wave per node, 4 waves per block
    const int gemmBlocks = 1024;

    // ---- fold weights (independent of CSR) ----
    for (int l = 0; l < 3; l++) {
        float* W1 = Wc + l * 4480;
        float* W2 = W1 + 4096;
        float* cv = W2 + 320;
        k_combine<<<1, TPB, 0, stream>>>(wn[l], bn[l], we[l], be[l], wc[l], bc[l], W1, W2, cv);
    }

    // ---- build CSR by dst ----
    hipMemsetAsync(row_start, 0, (size_t)N * 4, stream);
    k_hist<<<nbE, TPB, 0, stream>>>(dst, row_start, E);
    k_scan1<<<nbN, TPB, 0, stream>>>(row_start, partials, N);
    k_scan2<<<1, 1024, 0, stream>>>(partials, nbN);
    k_scan3<<<nbN, TPB, 0, stream>>>(row_start, partials, cursor, N, E);
    k_scatter<<<nbE, TPB, 0, stream>>>(src, dst, cursor, csr_e, csr_src, E);

    // ---- 3 edge-conv layers ----
    for (int l = 0; l < 3; l++) {
        const float* W1 = Wc + l * 4480;
        const float* W2 = W1 + 4096;
        const float* cv = W2 + 320;
        const float* h_in = (l == 0) ? x : bufB;
        k_gemm64<<<gemmBlocks, TPB, 0, stream>>>(h_in, W1, p, N, l == 0 ? 0 : 1);
        k_agg<<<nodeBlocks, TPB, 0, stream>>>(p, row_start, csr_e, csr_src, ea, W2, cv, bufB, N);
    }

    // ---- GAT ----
    k_gemm_gat<<<gemmBlocks, TPB, 0, stream>>>(bufB, wgat, bufG, N);
    k_att<<<N, 128, 0, stream>>>(bufG, att_src, att_dst, asrc, adst, N);
    k_gat_agg<<<nodeBlocks, TPB, 0, stream>>>(bufG, row_start, csr_src, asrc, adst, bgat, out, N);
}

// Round 2
// 839.115 us; speedup vs baseline: 1.2790x; 1.2790x over previous
//
#include <hip/hip_runtime.h>
#include <math.h>

// ---------------------------------------------------------------------------
// GraphNet: 3x EdgeConv (fully linearized) + GAT(2 heads, concat=False)
//
// EdgeConv layer l:
//   out[d] = (Σ_{e→d} h[src_e]) @ W1_l + B5[d] @ W2_l + deg[d]·c_l
//   where W1 = wn@wc_top, W2 = we@wc_bot, c = bn@wc_top + be@wc_bot + bc,
//   B5[d] = Σ_{e→d} ea_e  (layer-independent, computed once),
//   deg[d] from CSR row_start.
// Aggregation: CSR gather, 4 edges per wave-instruction (16 lanes x float4).
// ---------------------------------------------------------------------------

#define TPB 256

// ---------------- CSR build ----------------
__global__ __launch_bounds__(TPB) void k_hist(const int* __restrict__ dst, int* __restrict__ deg, int E) {
    int e = blockIdx.x * TPB + threadIdx.x;
    if (e < E) atomicAdd(&deg[dst[e]], 1);
}

__global__ __launch_bounds__(TPB) void k_scan1(int* __restrict__ data, int* __restrict__ partials, int n) {
    __shared__ int s[TPB];
    int i = blockIdx.x * TPB + threadIdx.x;
    int v = (i < n) ? data[i] : 0;
    s[threadIdx.x] = v;
    __syncthreads();
    for (int off = 1; off < TPB; off <<= 1) {
        int t = (threadIdx.x >= off) ? s[threadIdx.x - off] : 0;
        __syncthreads();
        s[threadIdx.x] += t;
        __syncthreads();
    }
    if (i < n) data[i] = s[threadIdx.x] - v;  // exclusive
    if (threadIdx.x == TPB - 1) partials[blockIdx.x] = s[TPB - 1];
}

__global__ __launch_bounds__(1024) void k_scan2(int* __restrict__ partials, int nb) {
    __shared__ int s[1024];
    int v = (threadIdx.x < nb) ? partials[threadIdx.x] : 0;
    s[threadIdx.x] = v;
    __syncthreads();
    for (int off = 1; off < 1024; off <<= 1) {
        int t = (threadIdx.x >= off) ? s[threadIdx.x - off] : 0;
        __syncthreads();
        s[threadIdx.x] += t;
        __syncthreads();
    }
    if (threadIdx.x < nb) partials[threadIdx.x] = s[threadIdx.x] - v;  // exclusive
}

__global__ __launch_bounds__(TPB) void k_scan3(int* __restrict__ data, const int* __restrict__ partials,
                                               int* __restrict__ cursor, int n, int total) {
    int i = blockIdx.x * TPB + threadIdx.x;
    if (i < n) {
        int v = data[i] + partials[blockIdx.x];
        data[i] = v;
        cursor[i] = v;
    }
    if (i == 0) data[n] = total;
}

__global__ __launch_bounds__(TPB) void k_scatter(const int* __restrict__ src, const int* __restrict__ dst,
                                                 int* __restrict__ cursor, int* __restrict__ csr_e,
                                                 int* __restrict__ csr_src, int E) {
    int e = blockIdx.x * TPB + threadIdx.x;
    if (e < E) {
        int d = dst[e];
        int idx = atomicAdd(&cursor[d], 1);
        csr_e[idx] = e;
        csr_src[idx] = src[e];
    }
}

// ---------------- weight folding (per layer, 1 block) ----------------
__global__ __launch_bounds__(TPB) void k_combine(const float* __restrict__ wn, const float* __restrict__ bn,
                                                 const float* __restrict__ we, const float* __restrict__ be,
                                                 const float* __restrict__ wc, const float* __restrict__ bc,
                                                 float* __restrict__ W1, float* __restrict__ W2,
                                                 float* __restrict__ cv) {
    int tid = threadIdx.x;
    for (int idx = tid; idx < 64 * 64; idx += TPB) {
        int i = idx >> 6, j = idx & 63;
        float acc = 0.f;
        #pragma unroll 8
        for (int k = 0; k < 64; k++) acc = fmaf(wn[i * 64 + k], wc[k * 64 + j], acc);
        W1[idx] = acc;
    }
    for (int idx = tid; idx < 5 * 64; idx += TPB) {
        int i = idx >> 6, j = idx & 63;
        float acc = 0.f;
        #pragma unroll 8
        for (int k = 0; k < 64; k++) acc = fmaf(we[i * 64 + k], wc[(64 + k) * 64 + j], acc);
        W2[idx] = acc;
    }
    for (int j = tid; j < 64; j += TPB) {
        float acc = bc[j];
        for (int k = 0; k < 64; k++) {
            acc = fmaf(bn[k], wc[k * 64 + j], acc);
            acc = fmaf(be[k], wc[(64 + k) * 64 + j], acc);
        }
        cv[j] = acc;
    }
}

// ---------------- B5[d] = sum of ea over incoming edges (once) ----------------
__global__ __launch_bounds__(TPB) void k_aggB5(const int* __restrict__ row_start, const int* __restrict__ csr_e,
                                               const float* __restrict__ EA, float* __restrict__ B5, int n) {
    int wave = threadIdx.x >> 6, lane = threadIdx.x & 63;
    for (int node = blockIdx.x * 4 + wave; node < n; node += gridDim.x * 4) {
        int beg = row_start[node], end = row_start[node + 1];
        float b0 = 0.f, b1 = 0.f, b2 = 0.f, b3 = 0.f, b4 = 0.f;
        for (int chunk = beg; chunk < end; chunk += 64) {
            int j = chunk + lane;
            if (j < end) {
                int e = csr_e[j];
                const float* eap = EA + (size_t)e * 5;
                b0 += eap[0]; b1 += eap[1]; b2 += eap[2]; b3 += eap[3]; b4 += eap[4];
            }
        }
        #pragma unroll
        for (int off = 1; off < 64; off <<= 1) {
            b0 += __shfl_xor(b0, off);
            b1 += __shfl_xor(b1, off);
            b2 += __shfl_xor(b2, off);
            b3 += __shfl_xor(b3, off);
            b4 += __shfl_xor(b4, off);
        }
        if (lane == 0) {
            float* bp = B5 + (size_t)node * 5;
            bp[0] = b0; bp[1] = b1; bp[2] = b2; bp[3] = b3; bp[4] = b4;
        }
    }
}

// ---------------- A[d] = sum of H[src_e] (pure gather-sum, 4 edges/instr) ----
__global__ __launch_bounds__(TPB) void k_aggA(const float* __restrict__ H, const int* __restrict__ row_start,
                                              const int* __restrict__ csr_src, float* __restrict__ OUT, int n) {
    int wave = threadIdx.x >> 6, lane = threadIdx.x & 63;
    int g = lane >> 4;            // edge subgroup 0..3
    int c4 = (lane & 15) * 4;     // column base
    for (int node = blockIdx.x * 4 + wave; node < n; node += gridDim.x * 4) {
        int beg = row_start[node], end = row_start[node + 1];
        float ax = 0.f, ay = 0.f, az = 0.f, aw = 0.f;
        for (int chunk = beg; chunk < end; chunk += 64) {
            int cdeg = min(end - chunk, 64);
            int s_l = (chunk + lane < end) ? csr_src[chunk + lane] : 0;
            int iters = (cdeg + 3) >> 2;
            for (int it = 0; it < iters; it++) {
                int el = g + 4 * it;
                int se = __shfl(s_l, el);
                if (el < cdeg) {
                    const float4 v = *reinterpret_cast<const float4*>(&H[(size_t)se * 64 + c4]);
                    ax += v.x; ay += v.y; az += v.z; aw += v.w;
                }
            }
        }
        ax += __shfl_xor(ax, 16); ay += __shfl_xor(ay, 16); az += __shfl_xor(az, 16); aw += __shfl_xor(aw, 16);
        ax += __shfl_xor(ax, 32); ay += __shfl_xor(ay, 32); az += __shfl_xor(az, 32); aw += __shfl_xor(aw, 32);
        if (g == 0) {
            float4 r; r.x = ax; r.y = ay; r.z = az; r.w = aw;
            *reinterpret_cast<float4*>(&OUT[(size_t)node * 64 + c4]) = r;
        }
    }
}

// ---------------- EdgeConv GEMM+epilogue: h' = relu(A@W1 + B5@W2 + deg*c) ----
__global__ __launch_bounds__(TPB) void k_gemm_ec(const float* __restrict__ A, const float* __restrict__ W1,
                                                 const float* __restrict__ W2, const float* __restrict__ cv,
                                                 const float* __restrict__ B5, const int* __restrict__ row_start,
                                                 float* __restrict__ OUT, int n) {
    __shared__ float Ws[64 * 64];
    for (int i = threadIdx.x; i < 64 * 64; i += TPB) Ws[i] = W1[i];
    __syncthreads();
    int wave = threadIdx.x >> 6, lane = threadIdx.x & 63;
    float w2r0 = W2[0 * 64 + lane], w2r1 = W2[1 * 64 + lane], w2r2 = W2[2 * 64 + lane];
    float w2r3 = W2[3 * 64 + lane], w2r4 = W2[4 * 64 + lane];
    float cl = cv[lane];
    for (int row = blockIdx.x * 4 + wave; row < n; row += gridDim.x * 4) {
        float av = A[(size_t)row * 64 + lane];
        float acc = 0.f;
        #pragma unroll
        for (int k = 0; k < 64; k++) acc = fmaf(__shfl(av, k), Ws[k * 64 + lane], acc);
        const float* bp = B5 + (size_t)row * 5;
        float deg = (float)(row_start[row + 1] - row_start[row]);
        float q = deg * cl;
        q = fmaf(bp[0], w2r0, q);
        q = fmaf(bp[1], w2r1, q);
        q = fmaf(bp[2], w2r2, q);
        q = fmaf(bp[3], w2r3, q);
        q = fmaf(bp[4], w2r4, q);
        OUT[(size_t)row * 64 + lane] = fmaxf(acc + q, 0.f);
    }
}

// ---------------- GAT GEMM + attention scores fused ----------------
__global__ __launch_bounds__(TPB) void k_gemm_gat(const float* __restrict__ H, const float* __restrict__ W,
                                                  const float* __restrict__ att_src, const float* __restrict__ att_dst,
                                                  float* __restrict__ G, float* __restrict__ asrc,
                                                  float* __restrict__ adst, int n) {
    __shared__ float Ws[64 * 128];
    for (int i = threadIdx.x; i < 64 * 128; i += TPB) Ws[i] = W[i];
    __syncthreads();
    int wave = threadIdx.x >> 6, lane = threadIdx.x & 63;
    float as0 = att_src[lane], as1 = att_src[64 + lane];
    float ad0 = att_dst[lane], ad1 = att_dst[64 + lane];
    for (int row = blockIdx.x * 4 + wave; row < n; row += gridDim.x * 4) {
        float hv = H[(size_t)row * 64 + lane];  // already relu'd
        float a0 = 0.f, a1 = 0.f;
        #pragma unroll
        for (int k = 0; k < 64; k++) {
            float b = __shfl(hv, k);
            a0 = fmaf(b, Ws[k * 128 + lane], a0);
            a1 = fmaf(b, Ws[k * 128 + 64 + lane], a1);
        }
        G[(size_t)row * 128 + lane] = a0;
        G[(size_t)row * 128 + 64 + lane] = a1;
        float s0 = a0 * as0, s1 = a1 * as1, d0 = a0 * ad0, d1 = a1 * ad1;
        #pragma unroll
        for (int off = 1; off < 64; off <<= 1) {
            s0 += __shfl_xor(s0, off);
            s1 += __shfl_xor(s1, off);
            d0 += __shfl_xor(d0, off);
            d1 += __shfl_xor(d1, off);
        }
        if (lane == 0) {
            float2 sv; sv.x = s0; sv.y = s1;
            float2 dv; dv.x = d0; dv.y = d1;
            *reinterpret_cast<float2*>(&asrc[(size_t)row * 2]) = sv;
            *reinterpret_cast<float2*>(&adst[(size_t)row * 2]) = dv;
        }
    }
}

// ---------------- GAT aggregation: online segment softmax + weighted sum ----
__global__ __launch_bounds__(TPB) void k_gat_agg(const float* __restrict__ G, const int* __restrict__ row_start,
                                                 const int* __restrict__ csr_src, const float* __restrict__ asrc,
                                                 const float* __restrict__ adst, const float* __restrict__ bgat,
                                                 float* __restrict__ OUT, int n) {
    int wave = threadIdx.x >> 6, lane = threadIdx.x & 63;
    int g = lane >> 4;
    int c4 = (lane & 15) * 4;
    for (int node = blockIdx.x * 4 + wave; node < n; node += gridDim.x * 4) {
        int beg = row_start[node], end = row_start[node + 1];
        float2 adv = *reinterpret_cast<const float2*>(&adst[(size_t)node * 2]);
        float m0 = -INFINITY, m1 = -INFINITY, d0 = 0.f, d1 = 0.f;
        float A0x = 0.f, A0y = 0.f, A0z = 0.f, A0w = 0.f;
        float A1x = 0.f, A1y = 0.f, A1z = 0.f, A1w = 0.f;
        for (int chunk = beg; chunk < end; chunk += 64) {
            int cdeg = min(end - chunk, 64);
            bool valid = (lane < cdeg);
            int s_l = valid ? csr_src[chunk + lane] : 0;
            float al0 = -INFINITY, al1 = -INFINITY;
            if (valid) {
                float2 av = *reinterpret_cast<const float2*>(&asrc[(size_t)s_l * 2]);
                float t0 = av.x + adv.x, t1 = av.y + adv.y;
                al0 = (t0 > 0.f) ? t0 : 0.2f * t0;
                al1 = (t1 > 0.f) ? t1 : 0.2f * t1;
            }
            // chunk max (allreduce)
            float cm0 = al0, cm1 = al1;
            #pragma unroll
            for (int off = 1; off < 64; off <<= 1) {
                cm0 = fmaxf(cm0, __shfl_xor(cm0, off));
                cm1 = fmaxf(cm1, __shfl_xor(cm1, off));
            }
            float nm0 = fmaxf(m0, cm0), nm1 = fmaxf(m1, cm1);
            float sc0 = __expf(m0 - nm0), sc1 = __expf(m1 - nm1);  // 0 on first chunk
            float w0 = valid ? __expf(al0 - nm0) : 0.f;
            float w1 = valid ? __expf(al1 - nm1) : 0.f;
            float cd0 = w0, cd1 = w1;
            #pragma unroll
            for (int off = 1; off < 64; off <<= 1) {
                cd0 += __shfl_xor(cd0, off);
                cd1 += __shfl_xor(cd1, off);
            }
            d0 = d0 * sc0 + cd0;
            d1 = d1 * sc1 + cd1;
            A0x *= sc0; A0y *= sc0; A0z *= sc0; A0w *= sc0;
            A1x *= sc1; A1y *= sc1; A1z *= sc1; A1w *= sc1;
            m0 = nm0; m1 = nm1;
            int iters = (cdeg + 3) >> 2;
            for (int it = 0; it < iters; it++) {
                int el = g + 4 * it;
                int se = __shfl(s_l, el);
                float w0e = __shfl(w0, el);
                float w1e = __shfl(w1, el);
                if (el < cdeg) {
                    const float4 g0 = *reinterpret_cast<const float4*>(&G[(size_t)se * 128 + c4]);
                    const float4 g1 = *reinterpret_cast<const float4*>(&G[(size_t)se * 128 + 64 + c4]);
                    A0x = fmaf(w0e, g0.x, A0x); A0y = fmaf(w0e, g0.y, A0y);
                    A0z = fmaf(w0e, g0.z, A0z); A0w = fmaf(w0e, g0.w, A0w);
                    A1x = fmaf(w1e, g1.x, A1x); A1y = fmaf(w1e, g1.y, A1y);
                    A1z = fmaf(w1e, g1.z, A1z); A1w = fmaf(w1e, g1.w, A1w);
                }
            }
        }
        #pragma unroll
        for (int off = 16; off < 64; off <<= 1) {
            A0x += __shfl_xor(A0x, off); A0y += __shfl_xor(A0y, off);
            A0z += __shfl_xor(A0z, off); A0w += __shfl_xor(A0w, off);
            A1x += __shfl_xor(A1x, off); A1y += __shfl_xor(A1y, off);
            A1z += __shfl_xor(A1z, off); A1w += __shfl_xor(A1w, off);
        }
        if (g == 0) {
            const float4 bg = *reinterpret_cast<const float4*>(&bgat[c4]);
            float r0 = 1.f / (d0 + 1e-16f), r1 = 1.f / (d1 + 1e-16f);
            float4 r;
            r.x = 0.5f * (A0x * r0 + A1x * r1) + bg.x;
            r.y = 0.5f * (A0y * r0 + A1y * r1) + bg.y;
            r.z = 0.5f * (A0z * r0 + A1z * r1) + bg.z;
            r.w = 0.5f * (A0w * r0 + A1w * r1) + bg.w;
            *reinterpret_cast<float4*>(&OUT[(size_t)node * 64 + c4]) = r;
        }
    }
}

extern "C" void kernel_launch(void* const* d_in, const int* in_sizes, int n_in,
                              void* d_out, int out_size, void* d_ws, size_t ws_size,
                              hipStream_t stream) {
    const float* x   = (const float*)d_in[0];
    const int*   ei  = (const int*)d_in[1];
    const float* ea  = (const float*)d_in[2];
    const int N = in_sizes[0] / 64;
    const int E = in_sizes[1] / 2;
    const int* src = ei;
    const int* dst = ei + E;

    const float* wn[3] = {(const float*)d_in[3],  (const float*)d_in[9],  (const float*)d_in[15]};
    const float* bn[3] = {(const float*)d_in[4],  (const float*)d_in[10], (const float*)d_in[16]};
    const float* we[3] = {(const float*)d_in[5],  (const float*)d_in[11], (const float*)d_in[17]};
    const float* be[3] = {(const float*)d_in[6],  (const float*)d_in[12], (const float*)d_in[18]};
    const float* wc[3] = {(const float*)d_in[7],  (const float*)d_in[13], (const float*)d_in[19]};
    const float* bc[3] = {(const float*)d_in[8],  (const float*)d_in[14], (const float*)d_in[20]};
    const float* wgat    = (const float*)d_in[21];
    const float* att_src = (const float*)d_in[22];
    const float* att_dst = (const float*)d_in[23];
    const float* bgat    = (const float*)d_in[24];

    // workspace carve-up (256B aligned)
    char* ws = (char*)d_ws;
    size_t off = 0;
    auto alloc = [&](size_t bytes) -> void* {
        void* p = ws + off;
        off = (off + bytes + 255) & ~(size_t)255;
        return p;
    };
    int*   row_start = (int*)alloc((size_t)(N + 1) * 4);
    int*   cursor    = (int*)alloc((size_t)N * 4);
    int*   partials  = (int*)alloc(1024 * 4);
    int*   csr_e     = (int*)alloc((size_t)E * 4);
    int*   csr_src   = (int*)alloc((size_t)E * 4);
    float* Wc        = (float*)alloc((size_t)3 * 4480 * 4);   // per layer: W1(4096) W2(320) c(64)
    float* B5        = (float*)alloc((size_t)N * 5 * 4);
    float* bufH      = (float*)alloc((size_t)N * 64 * 4);     // layer output h
    float* bufG      = (float*)alloc((size_t)N * 128 * 4);    // A aliases lower half; later G
    float* asrc      = (float*)alloc((size_t)N * 2 * 4);
    float* adst      = (float*)alloc((size_t)N * 2 * 4);
    float* bufA = bufG;     // [N,64] alias — dead before G is written
    float* out = (float*)d_out;

    const int nbN = (N + TPB - 1) / TPB;
    const int nbE = (E + TPB - 1) / TPB;
    const int nodeBlocks = (N + 3) / 4;  // 1 wave per node, 4 waves per block
    const int gemmBlocks = 1024;

    // ---- fold weights ----
    for (int l = 0; l < 3; l++) {
        float* W1 = Wc + l * 4480;
        float* W2 = W1 + 4096;
        float* cv = W2 + 320;
        k_combine<<<1, TPB, 0, stream>>>(wn[l], bn[l], we[l], be[l], wc[l], bc[l], W1, W2, cv);
    }

    // ---- build CSR by dst ----
    hipMemsetAsync(row_start, 0, (size_t)N * 4, stream);
    k_hist<<<nbE, TPB, 0, stream>>>(dst, row_start, E);
    k_scan1<<<nbN, TPB, 0, stream>>>(row_start, partials, N);
    k_scan2<<<1, 1024, 0, stream>>>(partials, nbN);
    k_scan3<<<nbN, TPB, 0, stream>>>(row_start, partials, cursor, N, E);
    k_scatter<<<nbE, TPB, 0, stream>>>(src, dst, cursor, csr_e, csr_src, E);

    // ---- one-time edge-attr aggregation ----
    k_aggB5<<<nodeBlocks, TPB, 0, stream>>>(row_start, csr_e, ea, B5, N);

    // ---- 3 edge-conv layers ----
    for (int l = 0; l < 3; l++) {
        const float* W1 = Wc + l * 4480;
        const float* W2 = W1 + 4096;
        const float* cv = W2 + 320;
        const float* h_in = (l == 0) ? x : bufH;
        k_aggA<<<nodeBlocks, TPB, 0, stream>>>(h_in, row_start, csr_src, bufA, N);
        k_gemm_ec<<<gemmBlocks, TPB, 0, stream>>>(bufA, W1, W2, cv, B5, row_start, bufH, N);
    }

    // ---- GAT ----
    k_gemm_gat<<<gemmBlocks, TPB, 0, stream>>>(bufH, wgat, att_src, att_dst, bufG, asrc, adst, N);
    k_gat_agg<<<nodeBlocks, TPB, 0, stream>>>(bufG, row_start, csr_src, asrc, adst, bgat, out, N);
}